// Round 17
// baseline (283.352 us; speedup 1.0000x reference)
//
#include <hip/hip_runtime.h>
#include <math.h>

#define HH 64
#define WW 64
#define BATCH 16
#define CINX 16
#define CHID 128
#define LNK 5

// ws layout (floats)
#define OFF_F      0
#define N_F        (BATCH*32*HH*WW)          // 2097152
#define OFF_FLOWS  (OFF_F + N_F)
#define N_FLOWS    (BATCH*2*LNK*HH*WW)       // 655360
#define OFF_WF     (OFF_FLOWS + N_FLOWS)     // 2752512
#define N_WF       (32*25*10)                // 8000
#define OFF_BRS    (OFF_WF + N_WF)
#define OFF_BHS    (OFF_BRS + 128)
#define OFF_ERF    (OFF_BHS + 128)           // einsum frags bf16 (81920 each gate)
#define OFF_EHF    (OFF_ERF + 40960)
#define OFF_XRF    (OFF_EHF + 40960)         // xconv im2col frags bf16 (fallback)
#define OFF_XHF    (OFF_XRF + 26624)
#define OFF_XGF    (OFF_XHF + 26624)         // fgen frags bf16 (138240)
#define OFF_X2R    (OFF_XGF + 69120)         // xconv direct frags bf16 (61440 each)
#define OFF_X2H    (OFF_X2R + 30720)
#define OFF_HT     (OFF_X2H + 30720)         // 3026496; hT f32 [b][y][x][c]
#define N_HT       (BATCH*HH*WW*CHID)        // 8388608 floats = 33.5 MB
#define NEED_WS_BYTES ((size_t)(OFF_HT + N_HT) * 4)   // ~45.7 MB

// prep region boundaries (element indices)
#define P_WF   8000
#define P_B    (P_WF + 128)                  // 8128
#define P_EF   (P_B + 81920)                 // 90048
#define P_XF   (P_EF + 53248)                // 143296
#define P_GF   (P_XF + 138240)               // 281536
#define P_X2   (P_GF + 61440)                // 342976

typedef short bf16x8 __attribute__((ext_vector_type(8)));
typedef float f32x4  __attribute__((ext_vector_type(4)));
#define MFMA(a,b,c) __builtin_amdgcn_mfma_f32_16x16x32_bf16((a),(b),(c),0,0,0)

__device__ __forceinline__ unsigned short f2b(float f) {
  unsigned u = __builtin_bit_cast(unsigned, f);
  u += 0x7fffu + ((u >> 16) & 1u);           // RNE
  return (unsigned short)(u >> 16);
}

#define SWZ(byte, row) ((byte) ^ (((row) & 7) << 4))
// stronger tile swizzle: XOR byte bits 4,5 with c0, c2 (bijective; keeps
// 16B-aligned reads aligned). 16-way -> 8-way on stride-32B staging writes.
#define SWZX(byte, c) ((byte) ^ ((((c) & 1) << 4) ^ ((((c) >> 2) & 1) << 5)))

// XCD-aware bijective swizzle: grid = 1024 = 8 XCDs x 128.
__device__ __forceinline__ int xcd_swz(int p) {
  return (p & 7) * 128 + (p >> 3);
}

// ---------------- prep: fragment weights, pre-sum biases --------
__global__ __launch_bounds__(256) void prep_kernel(
    const float* __restrict__ wxr_w, const float* __restrict__ wxh_w,
    const float* __restrict__ whr_w, const float* __restrict__ whh_w,
    const float* __restrict__ whr_b, const float* __restrict__ whh_b,
    const float* __restrict__ gx_w,  const float* __restrict__ gh_w,
    const float* __restrict__ gf_w,
    float* __restrict__ wfT,
    float* __restrict__ brs,  float* __restrict__ bhs,
    unsigned short* __restrict__ erF, unsigned short* __restrict__ ehF,
    unsigned short* __restrict__ xrF, unsigned short* __restrict__ xhF,
    unsigned short* __restrict__ xgF,
    unsigned short* __restrict__ x2rF, unsigned short* __restrict__ x2hF)
{
  int i = blockIdx.x * 256 + threadIdx.x;
  if (i < P_WF) {
    int k = i / 10, o = i % 10;              // wfT[k][o], k = cin*25+tap
    int cin = k / 25, tap = k % 25;
    wfT[i] = gf_w[(o*32 + cin)*25 + tap];
  } else if (i < P_B) {
    int o = i - P_WF;
    float sr = 0.f, sh = 0.f;
    for (int l = 0; l < LNK; ++l) { sr += whr_b[l*128 + o]; sh += whh_b[l*128 + o]; }
    brs[o] = sr; bhs[o] = sh;
  } else if (i < P_EF) {
    // einsum A-frags: j = (((l*4+ks)*8+m)*64 + lane)*8 + jj
    int j = i - P_B;
    int jj = j & 7, lane = (j >> 3) & 63, m = (j >> 9) & 7, ks = (j >> 12) & 3, l = j >> 14;
    int o = m*16 + (lane & 15);
    int c = ks*32 + ((lane >> 4) << 3) + jj;
    erF[j] = f2b(whr_w[(l*128 + o)*128 + c]);
    ehF[j] = f2b(whh_w[(l*128 + o)*128 + c]);
  } else if (i < P_XF) {
    // xconv im2col A-frags (fuse3 fallback): k padded 400->416
    int j = i - P_EF;
    int jj = j & 7, lane = (j >> 3) & 63, m = (j >> 9) & 7, ks = j >> 12;
    int o = m*16 + (lane & 15);
    int k = ks*32 + ((lane >> 4) << 3) + jj;
    xrF[j] = (k < 400) ? f2b(wxr_w[o*400 + k]) : (unsigned short)0;
    xhF[j] = (k < 400) ? f2b(wxh_w[o*400 + k]) : (unsigned short)0;
  } else if (i < P_GF) {
    // fgen A-frags: j = ((((ch*15 + kw*3 + khp)*2 + mo)*64 + lane)*8 + jj
    int j = i - P_XF;
    int jj = j & 7, lane = (j >> 3) & 63;
    int r2 = j >> 9;
    int mo = r2 & 1;
    int r3 = r2 >> 1;
    int khp = r3 % 3, kw = (r3 / 3) % 5, ch = r3 / 15;
    int q = lane >> 4;
    int k = q*8 + jj;
    int kh = khp*2 + (k >> 4);
    int cin_l = k & 15;
    int o = mo*16 + (lane & 15);
    float val = 0.f;
    if (kh < 5) {
      int tap = kh*5 + kw;
      val = (ch == 0) ? gx_w[(o*CINX + cin_l)*25 + tap]
                      : gh_w[(o*CHID + (ch-1)*16 + cin_l)*25 + tap];
    }
    xgF[j] = f2b(val);
  } else if (i < P_X2) {
    // xconv direct-conv A-frags: j = ((((kw*3+khp)*8 + wv)*64 + lane)*8 + jj
    int j = i - P_GF;
    int jj = j & 7, lane = (j >> 3) & 63;
    int wv = (j >> 9) & 7;
    int r3 = j >> 12;                        // 0..14
    int khp = r3 % 3, kw = r3 / 3;
    int o = wv*16 + (lane & 15);
    int k = ((lane >> 4) << 3) + jj;
    int kh = khp*2 + (k >> 4);
    int cin = k & 15;
    float vr = 0.f, vh = 0.f;
    if (kh < 5) {
      int off = o*400 + cin*25 + kh*5 + kw;
      vr = wxr_w[off]; vh = wxh_w[off];
    }
    x2rF[j] = f2b(vr); x2hF[j] = f2b(vh);
  }
}

// ------- fgen4: dbuf MFMA conv + fused hT emission; hoisted addressing ----
__global__ __launch_bounds__(512, 4) void fgen4_kernel(
    const float* __restrict__ x, const float* __restrict__ h,
    const unsigned short* __restrict__ xgF,
    const float* __restrict__ gxb, const float* __restrict__ ghb,
    float* __restrict__ f, float* __restrict__ hTout)
{
  __shared__ __align__(16) char tile[2][6*68*32];   // 26112 B
  __shared__ float crow[2][16][65];                 // 8320 B (padded)
  const int t = threadIdx.x;
  const int lb = xcd_swz(blockIdx.x);
  const int b = lb >> 6;
  const int y = lb & 63;
  const int lane = t & 63;
  const int w = t >> 6;
  const int mo = w >> 2, nf = w & 3;
  const int q = lane >> 4;
  const int s = q & 1;
  const int khq = q >> 1;
  const int cbase = nf*16 + (lane & 15);

  // zero row 5 of both buffers once (region is 64B-closed under SWZX)
  for (int i = t; i < 1088; i += 512) {
    int bsel = (i >= 544) ? 1 : 0;
    ((unsigned*)(tile[bsel] + 5*68*32))[i - bsel*544] = 0u;
  }

  const float* xp = x + b*CINX*HH*WW;
  const float* hp = h + b*CHID*HH*WW;
  float* hTrow = hTout ? hTout + (size_t)lb*8192 : nullptr;

  // chunk-invariant staging decomposition (registers, static-indexed)
  int goff[11], cbyt[11], crowi[11];
  #pragma unroll
  for (int k = 0; k < 11; ++k) {
    int i = t + k*512;
    if (i < 5440) {
      int cin = i / 340, rc = i - cin*340;
      int r = rc / 68, c = rc - r*68;
      int gy = y + r - 2, gxx = c - 2;
      bool vld = (gy >= 0 && gy < HH && gxx >= 0 && gxx < WW);
      goff[k] = vld ? (cin*4096 + gy*64 + gxx) : -1;
      int byte = ((r*68 + c)*16 + cin)*2;
      cbyt[k] = SWZX(byte, c);
      crowi[k] = (r == 2 && gxx >= 0 && gxx < WW) ? (cin*65 + gxx) : -1;
    } else {
      goff[k] = -1; cbyt[k] = -1; crowi[k] = -1;
    }
  }

  auto stage = [&](int ch, char* buf, float* crowp) {
    const float* src = (ch == 0) ? xp : hp + (ch - 1)*16*4096;
    #pragma unroll
    for (int k = 0; k < 11; ++k) {
      if (cbyt[k] < 0) continue;
      float v = (goff[k] >= 0) ? src[goff[k]] : 0.f;
      if (crowp && crowi[k] >= 0) crowp[crowi[k]] = v;
      *(unsigned short*)(buf + cbyt[k]) = f2b(v);
    }
  };

  f32x4 acc = (f32x4){0.f, 0.f, 0.f, 0.f};

  stage(0, tile[0], nullptr);
  __syncthreads();

  #pragma unroll 1
  for (int ch = 0; ch < 9; ++ch) {
    // flush chunk ch's center row (filled during stage(ch), synced) before
    // stage(ch+1) runs; stage(ch+1) writes crow[(ch+1)&1] != crow[ch&1].
    if (hTrow && ch > 0) {
      int xx = t >> 3, c2 = (t & 7) << 1;
      float* dst = hTrow + xx*128 + (ch-1)*16 + c2;
      dst[0] = crow[ch & 1][c2][xx];
      dst[1] = crow[ch & 1][c2+1][xx];
    }
    if (ch < 8) stage(ch + 1, tile[(ch + 1) & 1],
                      (hTrow) ? &crow[(ch + 1) & 1][0][0] : nullptr);
    const char* tb = tile[ch & 1];
    #pragma unroll
    for (int kw = 0; kw < 5; ++kw) {
      #pragma unroll
      for (int khp = 0; khp < 3; ++khp) {
        bf16x8 av = *(const bf16x8*)(xgF + (((ch*15 + kw*3 + khp)*2 + mo)*512) + lane*8);
        int c = cbase + kw;
        int kh = khp*2 + khq;
        int byte = ((kh*68 + c)*16 + s*8)*2;
        bf16x8 bv = *(const bf16x8*)(tb + SWZX(byte, c));
        acc = MFMA(av, bv, acc);
      }
    }
    __syncthreads();
  }

  #pragma unroll
  for (int r = 0; r < 4; ++r) {
    int o = mo*16 + q*4 + r;
    int pos = nf*16 + (lane & 15);
    float a = acc[r] + gxb[o] + ghb[o];
    f[(b*32 + o)*HH*WW + y*WW + pos] = a >= 0.f ? a : 0.2f*a;
  }
}

// ------- flowc2: flows = conv(f, gf), scalar f32 (flows MUST stay f32) -----
__global__ __launch_bounds__(640) void flowc2_kernel(
    const float* __restrict__ f, const float* __restrict__ wfT,
    const float* __restrict__ gfb, float* __restrict__ flows)
{
  __shared__ float tile[16*5*68];
  const int t = threadIdx.x;
  const int lb = xcd_swz(blockIdx.x);
  const int b = lb >> 6;
  const int y = lb & 63;
  const int o = t >> 6;
  const int pos = t & 63;

  float acc = gfb[o];

  #pragma unroll 1
  for (int ch = 0; ch < 2; ++ch) {
    const float* src = f + (b*32 + ch*16)*HH*WW;
    __syncthreads();
    for (int i = t; i < 16*5*68; i += 640) {
      int cin = i / 340, r2 = i % 340;
      int rr = r2 / 68, cc = r2 % 68;
      int gy = y + rr - 2, gx = cc - 2;
      tile[i] = (gy >= 0 && gy < HH && gx >= 0 && gx < WW)
                  ? src[cin*HH*WW + gy*WW + gx] : 0.f;
    }
    __syncthreads();
    const float* wbase = wfT + (ch*16*25)*10;
    #pragma unroll 1
    for (int ci = 0; ci < 16; ++ci) {
      #pragma unroll
      for (int kh = 0; kh < 5; ++kh) {
        #pragma unroll
        for (int kw = 0; kw < 5; ++kw) {
          float w = wbase[((ci*5 + kh)*5 + kw)*10 + o];
          acc = fmaf(w, tile[ci*340 + kh*68 + pos + kw], acc);
        }
      }
    }
  }
  flows[(b*10 + o)*HH*WW + y*WW + pos] = acc;
}

// ---- fuse7: 1024 thr, 16 waves; direct x-conv; coalesced hT gather ----
__global__ __launch_bounds__(1024, 8) void fuse7_kernel(
    const float* __restrict__ x, const float* __restrict__ hT,
    const float* __restrict__ flows,
    const unsigned short* __restrict__ erF, const unsigned short* __restrict__ ehF,
    const unsigned short* __restrict__ x2rF, const unsigned short* __restrict__ x2hF,
    const float* __restrict__ wxrb, const float* __restrict__ wxhb,
    const float* __restrict__ brs,  const float* __restrict__ bhs,
    float* __restrict__ out, int out_half)
{
  __shared__ __align__(16) char xtile[6*68*32];   // 13056 B
  __shared__ __align__(16) char warped[64*256];   // 16384 B
  __shared__ int   cidx[LNK*4*64];
  __shared__ float cwt[LNK*4*64];

  const int t = threadIdx.x;
  const int lb = xcd_swz(blockIdx.x);
  const int b = lb >> 6;
  const int y = lb & 63;
  const int lane = t & 63;
  const int w = t >> 6;            // 0..15
  const int wo = w & 7;            // o-stripe
  const int wp = w >> 3;           // pos half
  const int q = lane >> 4;
  const int s = q & 1;
  const int khq = q >> 1;

  if (t < 544) ((unsigned*)(xtile + 5*68*32))[t] = 0u;

  // stage x halo tile [6][68][16] bf16
  {
    const float* xp = x + b*CINX*HH*WW;
    for (int i = t; i < 5440; i += 1024) {
      int cin = i / 340, rc = i % 340;
      int r = rc / 68, c = rc % 68;
      int gy = y + r - 2, gx = c - 2;
      float v = (gy >= 0 && gy < HH && gx >= 0 && gx < WW)
                  ? xp[cin*4096 + gy*64 + gx] : 0.f;
      int byte = ((r*68 + c)*16 + cin)*2;
      *(unsigned short*)(xtile + SWZX(byte, c)) = f2b(v);
    }
  }

  // bilinear corners for 64 pos x 5 links
  if (t < 320) {
    int pos = t & 63; int l = t >> 6;
    float fx = flows[((b*2*LNK) + 2*l + 0)*HH*WW + y*WW + pos];
    float fy = flows[((b*2*LNK) + 2*l + 1)*HH*WW + y*WW + pos];
    float px = fx + (float)pos;
    float py = fy + (float)y;
    float x0f = floorf(px), y0f = floorf(py);
    float ax = px - x0f, ay = py - y0f;
    int ix0 = (int)x0f, iy0 = (int)y0f;
    #pragma unroll
    for (int k = 0; k < 4; ++k) {
      int dx = k & 1, dy = k >> 1;
      int ix = ix0 + dx, iy = iy0 + dy;
      float wgt = (dx ? ax : 1.f - ax) * (dy ? ay : 1.f - ay);
      bool inb = (ix >= 0 && ix < WW && iy >= 0 && iy < HH);
      int ixc = ix < 0 ? 0 : (ix > WW-1 ? WW-1 : ix);
      int iyc = iy < 0 ? 0 : (iy > HH-1 ? HH-1 : iy);
      cidx[(l*4 + k)*64 + pos] = iyc*WW + ixc;
      cwt [(l*4 + k)*64 + pos] = inb ? wgt : 0.f;
    }
  }
  __syncthreads();

  f32x4 accr[2], acch[2];
  #pragma unroll
  for (int f = 0; f < 2; ++f) {
    accr[f] = (f32x4){0.f,0.f,0.f,0.f};
    acch[f] = (f32x4){0.f,0.f,0.f,0.f};
  }

  // GEMM2: direct x-conv, 15 (kw,khp) steps x 2 col-frags x 2 gates
  #pragma unroll 1
  for (int kw = 0; kw < 5; ++kw) {
    #pragma unroll
    for (int khp = 0; khp < 3; ++khp) {
      bf16x8 ar = *(const bf16x8*)(x2rF + (((kw*3 + khp)*8 + wo)*512) + lane*8);
      bf16x8 ah = *(const bf16x8*)(x2hF + (((kw*3 + khp)*8 + wo)*512) + lane*8);
      int kh = khp*2 + khq;
      #pragma unroll
      for (int f = 0; f < 2; ++f) {
        int c = wp*32 + f*16 + (lane & 15) + kw;
        int byte = ((kh*68 + c)*16 + s*8)*2;
        bf16x8 bv = *(const bf16x8*)(xtile + SWZX(byte, c));
        accr[f] = MFMA(ar, bv, accr[f]);
        acch[f] = MFMA(ah, bv, acch[f]);
      }
    }
  }

  f32x4 tmph[2];
  tmph[0] = (f32x4){0.f,0.f,0.f,0.f};
  tmph[1] = (f32x4){0.f,0.f,0.f,0.f};

  // GEMM1: einsum, 5 chunks of K=128; coalesced gather from hT.
  const float* hTb = hT + (size_t)b*524288;
  const int gp  = t >> 4;
  const int sub = t & 15;
  #pragma unroll 1
  for (int l = 0; l < 5; ++l) {
    if (l) __syncthreads();
    float w0 = cwt[(l*4+0)*64 + gp], w1 = cwt[(l*4+1)*64 + gp];
    float w2 = cwt[(l*4+2)*64 + gp], w3 = cwt[(l*4+3)*64 + gp];
    int   i0 = cidx[(l*4+0)*64 + gp], i1 = cidx[(l*4+1)*64 + gp];
    int   i2 = cidx[(l*4+2)*64 + gp], i3 = cidx[(l*4+3)*64 + gp];
    const float* p0 = hTb + i0*128 + sub*8;
    const float* p1 = hTb + i1*128 + sub*8;
    const float* p2 = hTb + i2*128 + sub*8;
    const float* p3 = hTb + i3*128 + sub*8;
    unsigned pr[4];
    #pragma unroll
    for (int e4 = 0; e4 < 2; ++e4) {
      float4 c0 = *(const float4*)(p0 + e4*4);
      float4 c1 = *(const float4*)(p1 + e4*4);
      float4 c2 = *(const float4*)(p2 + e4*4);
      float4 c3 = *(const float4*)(p3 + e4*4);
      const float* c0p = (const float*)&c0;
      const float* c1p = (const float*)&c1;
      const float* c2p = (const float*)&c2;
      const float* c3p = (const float*)&c3;
      #pragma unroll
      for (int jp = 0; jp < 2; ++jp) {
        int e = jp << 1;
        float a0 = w0*c0p[e];   a0 = fmaf(w1, c1p[e], a0);
        a0 = fmaf(w2, c2p[e], a0); a0 = fmaf(w3, c3p[e], a0);
        float a1 = w0*c0p[e+1]; a1 = fmaf(w1, c1p[e+1], a1);
        a1 = fmaf(w2, c2p[e+1], a1); a1 = fmaf(w3, c3p[e+1], a1);
        pr[e4*2 + jp] = (unsigned)f2b(a0) | ((unsigned)f2b(a1) << 16);
      }
    }
    uint4 pv; pv.x = pr[0]; pv.y = pr[1]; pv.z = pr[2]; pv.w = pr[3];
    int cbyte = gp*256 + sub*16;
    *(uint4*)(warped + SWZ(cbyte, gp)) = pv;
    __syncthreads();
    #pragma unroll
    for (int ks = 0; ks < 4; ++ks) {
      bf16x8 ar = *(const bf16x8*)(erF + (((l << 2) + ks)*8 + wo)*512 + lane*8);
      bf16x8 ah = *(const bf16x8*)(ehF + (((l << 2) + ks)*8 + wo)*512 + lane*8);
      int k0 = (ks << 5) + (q << 3);
      #pragma unroll
      for (int f = 0; f < 2; ++f) {
        int col = wp*32 + (f << 4) + (lane & 15);
        bf16x8 bv = *(const bf16x8*)(warped + SWZ(col*256 + k0*2, col));
        accr[f] = MFMA(ar, bv, accr[f]);
        tmph[f] = MFMA(ah, bv, tmph[f]);
      }
    }
  }

  // epilogue: r=sigmoid(.), out = leaky(ch + r*th); z cancels.
  const int obase = (b*CHID)*HH*WW + y*WW;
  #pragma unroll
  for (int r = 0; r < 4; ++r) {
    int o = wo*16 + (q << 2) + r;
    float br_ = wxrb[o] + brs[o];
    float bh_ = wxhb[o];
    float bt_ = bhs[o];
    #pragma unroll
    for (int f = 0; f < 2; ++f) {
      int pos_ = wp*32 + (f << 4) + (lane & 15);
      float rg = 1.f / (1.f + expf(-(accr[f][r] + br_)));
      float hv = (acch[f][r] + bh_) + rg*(tmph[f][r] + bt_);
      hv = hv >= 0.f ? hv : 0.2f*hv;
      int idx = obase + o*HH*WW + pos_;
      out[idx] = hv;
      out[out_half + idx] = hv;
    }
  }
}

// ---------------- fuse3 (fallback when ws too small) -----------------------
__global__ __launch_bounds__(512, 4) void fuse3_kernel(
    const float* __restrict__ x, const float* __restrict__ h,
    const float* __restrict__ flows,
    const unsigned short* __restrict__ erF, const unsigned short* __restrict__ ehF,
    const unsigned short* __restrict__ xrF, const unsigned short* __restrict__ xhF,
    const float* __restrict__ wxrb, const float* __restrict__ wxhb,
    const float* __restrict__ brs,  const float* __restrict__ bhs,
    float* __restrict__ out, int out_half)
{
  __shared__ __align__(16) char smem[64*416*2];
  __shared__ int   cidx[LNK*4*64];
  __shared__ float cwt[LNK*4*64];

  const int t = threadIdx.x;
  const int lb = xcd_swz(blockIdx.x);
  const int b = lb >> 6;
  const int y = lb & 63;
  const int lane = t & 63;
  const int w = t >> 6;

  if (t < 320) {
    int pos = t & 63; int l = t >> 6;
    float fx = flows[((b*2*LNK) + 2*l + 0)*HH*WW + y*WW + pos];
    float fy = flows[((b*2*LNK) + 2*l + 1)*HH*WW + y*WW + pos];
    float px = fx + (float)pos;
    float py = fy + (float)y;
    float x0f = floorf(px), y0f = floorf(py);
    float ax = px - x0f, ay = py - y0f;
    int ix0 = (int)x0f, iy0 = (int)y0f;
    #pragma unroll
    for (int k = 0; k < 4; ++k) {
      int dx = k & 1, dy = k >> 1;
      int ix = ix0 + dx, iy = iy0 + dy;
      float wgt = (dx ? ax : 1.f - ax) * (dy ? ay : 1.f - ay);
      bool inb = (ix >= 0 && ix < WW && iy >= 0 && iy < HH);
      int ixc = ix < 0 ? 0 : (ix > WW-1 ? WW-1 : ix);
      int iyc = iy < 0 ? 0 : (iy > HH-1 ? HH-1 : iy);
      cidx[(l*4 + k)*64 + pos] = iyc*WW + ixc;
      cwt [(l*4 + k)*64 + pos] = inb ? wgt : 0.f;
    }
  }

  {
    const float* xp = x + b*CINX*HH*WW;
    for (int i = t; i < 64*416; i += 512) {
      int pos = i / 416; int k = i - pos*416;
      float val = 0.f;
      if (k < 400) {
        int cin = k / 25; int tap = k - cin*25;
        int kh = tap / 5; int kw = tap - kh*5;
        int gy = y + kh - 2, gxp = pos + kw - 2;
        if (gy >= 0 && gy < HH && gxp >= 0 && gxp < WW)
          val = xp[cin*4096 + gy*64 + gxp];
      }
      *(unsigned short*)(smem + SWZ(pos*832 + k*2, pos)) = f2b(val);
    }
  }
  __syncthreads();

  f32x4 accr[4], acch[4], tmph[4];
  #pragma unroll
  for (int f = 0; f < 4; ++f) {
    accr[f] = (f32x4){0.f,0.f,0.f,0.f};
    acch[f] = (f32x4){0.f,0.f,0.f,0.f};
    tmph[f] = (f32x4){0.f,0.f,0.f,0.f};
  }

  #pragma unroll 2
  for (int ks = 0; ks < 13; ++ks) {
    bf16x8 ar = *(const bf16x8*)(xrF + ((ks << 3) + w)*512 + lane*8);
    bf16x8 ah = *(const bf16x8*)(xhF + ((ks << 3) + w)*512 + lane*8);
    int k0 = (ks << 5) + ((lane >> 4) << 3);
    #pragma unroll
    for (int f = 0; f < 4; ++f) {
      int col = (f << 4) + (lane & 15);
      bf16x8 bv = *(const bf16x8*)(smem + SWZ(col*832 + k0*2, col));
      accr[f] = MFMA(ar, bv, accr[f]);
      acch[f] = MFMA(ah, bv, acch[f]);
    }
  }

  const float* hp = h + b*CHID*HH*WW;
  #pragma unroll 1
  for (int l = 0; l < 5; ++l) {
    __syncthreads();
    float w0 = cwt[(l*4+0)*64 + lane], w1 = cwt[(l*4+1)*64 + lane];
    float w2 = cwt[(l*4+2)*64 + lane], w3 = cwt[(l*4+3)*64 + lane];
    int   i0 = cidx[(l*4+0)*64 + lane], i1 = cidx[(l*4+1)*64 + lane];
    int   i2 = cidx[(l*4+2)*64 + lane], i3 = cidx[(l*4+3)*64 + lane];
    const float* hc = hp + (w << 4)*4096;
    #pragma unroll
    for (int jj = 0; jj < 8; ++jj) {
      const float* h0 = hc + (2*jj)*4096;
      const float* h1 = h0 + 4096;
      float a0 = w0*h0[i0]; a0 = fmaf(w1, h0[i1], a0);
      a0 = fmaf(w2, h0[i2], a0); a0 = fmaf(w3, h0[i3], a0);
      float a1 = w0*h1[i0]; a1 = fmaf(w1, h1[i1], a1);
      a1 = fmaf(w2, h1[i2], a1); a1 = fmaf(w3, h1[i3], a1);
      unsigned pr = (unsigned)f2b(a0) | ((unsigned)f2b(a1) << 16);
      int c0 = (w << 4) + 2*jj;
      *(unsigned*)(smem + SWZ(lane*256 + c0*2, lane)) = pr;
    }
    __syncthreads();
    #pragma unroll
    for (int ks = 0; ks < 4; ++ks) {
      bf16x8 ar = *(const bf16x8*)(erF + (((l << 2) + ks)*8 + w)*512 + lane*8);
      bf16x8 ah = *(const bf16x8*)(ehF + (((l << 2) + ks)*8 + w)*512 + lane*8);
      int k0 = (ks << 5) + ((lane >> 4) << 3);
      #pragma unroll
      for (int f = 0; f < 4; ++f) {
        int col = (f << 4) + (lane & 15);
        bf16x8 bv = *(const bf16x8*)(smem + SWZ(col*256 + k0*2, col));
        accr[f] = MFMA(ar, bv, accr[f]);
        tmph[f] = MFMA(ah, bv, tmph[f]);
      }
    }
  }

  const int obase = (b*CHID)*HH*WW + y*WW;
  #pragma unroll
  for (int r = 0; r < 4; ++r) {
    int o = (w << 4) + ((lane >> 4) << 2) + r;
    float br_ = wxrb[o] + brs[o];
    float bh_ = wxhb[o];
    float bt_ = bhs[o];
    #pragma unroll
    for (int f = 0; f < 4; ++f) {
      int pos_ = (f << 4) + (lane & 15);
      float rg = 1.f / (1.f + expf(-(accr[f][r] + br_)));
      float hv = (acch[f][r] + bh_) + rg*(tmph[f][r] + bt_);
      hv = hv >= 0.f ? hv : 0.2f*hv;
      int idx = obase + o*HH*WW + pos_;
      out[idx] = hv;
      out[out_half + idx] = hv;
    }
  }
}

extern "C" void kernel_launch(void* const* d_in, const int* in_sizes, int n_in,
                              void* d_out, int out_size, void* d_ws, size_t ws_size,
                              hipStream_t stream)
{
  const float* x     = (const float*)d_in[0];
  const float* h     = (const float*)d_in[1];
  const float* gx_w  = (const float*)d_in[2];
  const float* gx_b  = (const float*)d_in[3];
  const float* gh_w  = (const float*)d_in[4];
  const float* gh_b  = (const float*)d_in[5];
  const float* gf_w  = (const float*)d_in[6];
  const float* gf_b  = (const float*)d_in[7];
  const float* wxr_w = (const float*)d_in[10];
  const float* wxr_b = (const float*)d_in[11];
  const float* wxh_w = (const float*)d_in[12];
  const float* wxh_b = (const float*)d_in[13];
  const float* whr_w = (const float*)d_in[16];
  const float* whr_b = (const float*)d_in[17];
  const float* whh_w = (const float*)d_in[18];
  const float* whh_b = (const float*)d_in[19];
  float* out = (float*)d_out;
  float* wsf = (float*)d_ws;

  float* f_buf = wsf + OFF_F;
  float* flows = wsf + OFF_FLOWS;
  float* wfT   = wsf + OFF_WF;
  float* brs   = wsf + OFF_BRS;
  float* bhs   = wsf + OFF_BHS;
  unsigned short* erF  = (unsigned short*)(wsf + OFF_ERF);
  unsigned short* ehF  = (unsigned short*)(wsf + OFF_EHF);
  unsigned short* xrF  = (unsigned short*)(wsf + OFF_XRF);
  unsigned short* xhF  = (unsigned short*)(wsf + OFF_XHF);
  unsigned short* xgF  = (unsigned short*)(wsf + OFF_XGF);
  unsigned short* x2rF = (unsigned short*)(wsf + OFF_X2R);
  unsigned short* x2hF = (unsigned short*)(wsf + OFF_X2H);
  float* hT = wsf + OFF_HT;

  const bool big_ws = (ws_size >= NEED_WS_BYTES);

  prep_kernel<<<(P_X2 + 255)/256, 256, 0, stream>>>(
      wxr_w, wxh_w, whr_w, whh_w, whr_b, whh_b, gx_w, gh_w, gf_w,
      wfT, brs, bhs, erF, ehF, xrF, xhF, xgF, x2rF, x2hF);
  fgen4_kernel<<<BATCH*HH, 512, 0, stream>>>(x, h, xgF, gx_b, gh_b, f_buf,
                                             big_ws ? hT : nullptr);
  flowc2_kernel<<<BATCH*HH, 640, 0, stream>>>(f_buf, wfT, gf_b, flows);
  if (big_ws) {
    fuse7_kernel<<<BATCH*HH, 1024, 0, stream>>>(x, hT, flows, erF, ehF, x2rF, x2hF,
                                                wxr_b, wxh_b, brs, bhs, out, out_size/2);
  } else {
    fuse3_kernel<<<BATCH*HH, 512, 0, stream>>>(x, h, flows, erF, ehF, xrF, xhF,
                                               wxr_b, wxh_b, brs, bhs, out, out_size/2);
  }
}

// Round 18
// 245.158 us; speedup vs baseline: 1.1558x; 1.1558x over previous
//
#include <hip/hip_runtime.h>
#include <math.h>

#define HH 64
#define WW 64
#define BATCH 16
#define CINX 16
#define CHID 128
#define LNK 5

// ws layout (floats)
#define OFF_F      0
#define N_F        (BATCH*32*HH*WW)          // 2097152
#define OFF_FLOWS  (OFF_F + N_F)
#define N_FLOWS    (BATCH*2*LNK*HH*WW)       // 655360
#define OFF_WF     (OFF_FLOWS + N_FLOWS)     // 2752512
#define N_WF       (32*25*10)                // 8000
#define OFF_BRS    (OFF_WF + N_WF)
#define OFF_BHS    (OFF_BRS + 128)
#define OFF_ERF    (OFF_BHS + 128)           // einsum frags bf16 (81920 each gate)
#define OFF_EHF    (OFF_ERF + 40960)
#define OFF_XRF    (OFF_EHF + 40960)         // xconv im2col frags bf16 (fallback)
#define OFF_XHF    (OFF_XRF + 26624)
#define OFF_XGF    (OFF_XHF + 26624)         // fgen frags bf16 (138240)
#define OFF_X2R    (OFF_XGF + 69120)         // xconv direct frags bf16 (61440 each)
#define OFF_X2H    (OFF_X2R + 30720)
#define OFF_HT     (OFF_X2H + 30720)         // 3026496; hT f32 [b][y][x][c]
#define N_HT       (BATCH*HH*WW*CHID)        // 8388608 floats = 33.5 MB
#define NEED_WS_BYTES ((size_t)(OFF_HT + N_HT) * 4)   // ~45.7 MB

// prep region boundaries (element indices)
#define P_WF   8000
#define P_B    (P_WF + 128)                  // 8128
#define P_EF   (P_B + 81920)                 // 90048
#define P_XF   (P_EF + 53248)                // 143296
#define P_GF   (P_XF + 138240)               // 281536
#define P_X2   (P_GF + 61440)                // 342976

typedef short bf16x8 __attribute__((ext_vector_type(8)));
typedef float f32x4  __attribute__((ext_vector_type(4)));
#define MFMA(a,b,c) __builtin_amdgcn_mfma_f32_16x16x32_bf16((a),(b),(c),0,0,0)

__device__ __forceinline__ unsigned short f2b(float f) {
  unsigned u = __builtin_bit_cast(unsigned, f);
  u += 0x7fffu + ((u >> 16) & 1u);           // RNE
  return (unsigned short)(u >> 16);
}

#define SWZ(byte, row) ((byte) ^ (((row) & 7) << 4))
// tile swizzle: XOR byte bits 4,5 with c bits 0,2 (bijective; keeps 16B reads
// aligned). Measured r16: conflicts 12.65M -> 5.26M on fgen4 staging.
#define SWZX(byte, c) ((byte) ^ ((((c) & 1) << 4) ^ ((((c) >> 2) & 1) << 5)))

// XCD-aware bijective swizzle: grid = 1024 = 8 XCDs x 128.
__device__ __forceinline__ int xcd_swz(int p) {
  return (p & 7) * 128 + (p >> 3);
}

// ---------------- prep: fragment weights, pre-sum biases --------
__global__ __launch_bounds__(256) void prep_kernel(
    const float* __restrict__ wxr_w, const float* __restrict__ wxh_w,
    const float* __restrict__ whr_w, const float* __restrict__ whh_w,
    const float* __restrict__ whr_b, const float* __restrict__ whh_b,
    const float* __restrict__ gx_w,  const float* __restrict__ gh_w,
    const float* __restrict__ gf_w,
    float* __restrict__ wfT,
    float* __restrict__ brs,  float* __restrict__ bhs,
    unsigned short* __restrict__ erF, unsigned short* __restrict__ ehF,
    unsigned short* __restrict__ xrF, unsigned short* __restrict__ xhF,
    unsigned short* __restrict__ xgF,
    unsigned short* __restrict__ x2rF, unsigned short* __restrict__ x2hF)
{
  int i = blockIdx.x * 256 + threadIdx.x;
  if (i < P_WF) {
    int k = i / 10, o = i % 10;              // wfT[k][o], k = cin*25+tap
    int cin = k / 25, tap = k % 25;
    wfT[i] = gf_w[(o*32 + cin)*25 + tap];
  } else if (i < P_B) {
    int o = i - P_WF;
    float sr = 0.f, sh = 0.f;
    for (int l = 0; l < LNK; ++l) { sr += whr_b[l*128 + o]; sh += whh_b[l*128 + o]; }
    brs[o] = sr; bhs[o] = sh;
  } else if (i < P_EF) {
    // einsum A-frags: j = (((l*4+ks)*8+m)*64 + lane)*8 + jj
    int j = i - P_B;
    int jj = j & 7, lane = (j >> 3) & 63, m = (j >> 9) & 7, ks = (j >> 12) & 3, l = j >> 14;
    int o = m*16 + (lane & 15);
    int c = ks*32 + ((lane >> 4) << 3) + jj;
    erF[j] = f2b(whr_w[(l*128 + o)*128 + c]);
    ehF[j] = f2b(whh_w[(l*128 + o)*128 + c]);
  } else if (i < P_XF) {
    // xconv im2col A-frags (fuse3 fallback): k padded 400->416
    int j = i - P_EF;
    int jj = j & 7, lane = (j >> 3) & 63, m = (j >> 9) & 7, ks = j >> 12;
    int o = m*16 + (lane & 15);
    int k = ks*32 + ((lane >> 4) << 3) + jj;
    xrF[j] = (k < 400) ? f2b(wxr_w[o*400 + k]) : (unsigned short)0;
    xhF[j] = (k < 400) ? f2b(wxh_w[o*400 + k]) : (unsigned short)0;
  } else if (i < P_GF) {
    // fgen A-frags: j = ((((ch*15 + kw*3 + khp)*2 + mo)*64 + lane)*8 + jj
    int j = i - P_XF;
    int jj = j & 7, lane = (j >> 3) & 63;
    int r2 = j >> 9;
    int mo = r2 & 1;
    int r3 = r2 >> 1;
    int khp = r3 % 3, kw = (r3 / 3) % 5, ch = r3 / 15;
    int q = lane >> 4;
    int k = q*8 + jj;
    int kh = khp*2 + (k >> 4);
    int cin_l = k & 15;
    int o = mo*16 + (lane & 15);
    float val = 0.f;
    if (kh < 5) {
      int tap = kh*5 + kw;
      val = (ch == 0) ? gx_w[(o*CINX + cin_l)*25 + tap]
                      : gh_w[(o*CHID + (ch-1)*16 + cin_l)*25 + tap];
    }
    xgF[j] = f2b(val);
  } else if (i < P_X2) {
    // xconv direct-conv A-frags: j = ((((kw*3+khp)*8 + wv)*64 + lane)*8 + jj
    int j = i - P_GF;
    int jj = j & 7, lane = (j >> 3) & 63;
    int wv = (j >> 9) & 7;
    int r3 = j >> 12;                        // 0..14
    int khp = r3 % 3, kw = r3 / 3;
    int o = wv*16 + (lane & 15);
    int k = ((lane >> 4) << 3) + jj;
    int kh = khp*2 + (k >> 4);
    int cin = k & 15;
    float vr = 0.f, vh = 0.f;
    if (kh < 5) {
      int off = o*400 + cin*25 + kh*5 + kw;
      vr = wxr_w[off]; vh = wxh_w[off];
    }
    x2rF[j] = f2b(vr); x2hF[j] = f2b(vh);
  }
}

// ------- fgen4: dbuf MFMA conv + fused hT emission -------
// stage uses INLINE address recompute (r16 lesson: hoisting to register
// arrays serialized the loads; the VALU addr math is free latency-hiding).
__global__ __launch_bounds__(512, 4) void fgen4_kernel(
    const float* __restrict__ x, const float* __restrict__ h,
    const unsigned short* __restrict__ xgF,
    const float* __restrict__ gxb, const float* __restrict__ ghb,
    float* __restrict__ f, float* __restrict__ hTout)
{
  __shared__ __align__(16) char tile[2][6*68*32];   // 26112 B
  __shared__ float crow[2][16][65];                 // 8320 B (padded)
  const int t = threadIdx.x;
  const int lb = xcd_swz(blockIdx.x);
  const int b = lb >> 6;
  const int y = lb & 63;
  const int lane = t & 63;
  const int w = t >> 6;
  const int mo = w >> 2, nf = w & 3;
  const int q = lane >> 4;
  const int s = q & 1;
  const int khq = q >> 1;
  const int cbase = nf*16 + (lane & 15);

  // zero row 5 of both buffers once (region is 64B-closed under SWZX)
  for (int i = t; i < 1088; i += 512) {
    int bsel = (i >= 544) ? 1 : 0;
    ((unsigned*)(tile[bsel] + 5*68*32))[i - bsel*544] = 0u;
  }

  const float* xp = x + b*CINX*HH*WW;
  const float* hp = h + b*CHID*HH*WW;
  float* hTrow = hTout ? hTout + (size_t)lb*8192 : nullptr;

  auto stage = [&](int ch, char* buf, float* crowp) {
    const float* src = (ch == 0) ? xp : hp + (ch - 1)*16*4096;
    for (int i = t; i < 5440; i += 512) {
      int cin = i / 340, rc = i % 340;
      int r = rc / 68, c = rc % 68;
      int gy = y + r - 2, gx = c - 2;
      float v = (gy >= 0 && gy < HH && gx >= 0 && gx < WW)
                  ? src[cin*4096 + gy*64 + gx] : 0.f;
      if (crowp && r == 2 && gx >= 0 && gx < WW)
        crowp[cin*65 + gx] = v;
      int byte = ((r*68 + c)*16 + cin)*2;
      *(unsigned short*)(buf + SWZX(byte, c)) = f2b(v);
    }
  };

  f32x4 acc = (f32x4){0.f, 0.f, 0.f, 0.f};

  stage(0, tile[0], nullptr);
  __syncthreads();

  #pragma unroll 1
  for (int ch = 0; ch < 9; ++ch) {
    // flush chunk ch's center row (filled during stage(ch), synced) before
    // stage(ch+1) runs; stage(ch+1) writes crow[(ch+1)&1] != crow[ch&1].
    if (hTrow && ch > 0) {
      int xx = t >> 3, c2 = (t & 7) << 1;
      float* dst = hTrow + xx*128 + (ch-1)*16 + c2;
      dst[0] = crow[ch & 1][c2][xx];
      dst[1] = crow[ch & 1][c2+1][xx];
    }
    if (ch < 8) stage(ch + 1, tile[(ch + 1) & 1],
                      (hTrow) ? &crow[(ch + 1) & 1][0][0] : nullptr);
    const char* tb = tile[ch & 1];
    #pragma unroll
    for (int kw = 0; kw < 5; ++kw) {
      #pragma unroll
      for (int khp = 0; khp < 3; ++khp) {
        bf16x8 av = *(const bf16x8*)(xgF + (((ch*15 + kw*3 + khp)*2 + mo)*512) + lane*8);
        int c = cbase + kw;
        int kh = khp*2 + khq;
        int byte = ((kh*68 + c)*16 + s*8)*2;
        bf16x8 bv = *(const bf16x8*)(tb + SWZX(byte, c));
        acc = MFMA(av, bv, acc);
      }
    }
    __syncthreads();
  }

  #pragma unroll
  for (int r = 0; r < 4; ++r) {
    int o = mo*16 + q*4 + r;
    int pos = nf*16 + (lane & 15);
    float a = acc[r] + gxb[o] + ghb[o];
    f[(b*32 + o)*HH*WW + y*WW + pos] = a >= 0.f ? a : 0.2f*a;
  }
}

// ------- flowc2: flows = conv(f, gf), scalar f32 (flows MUST stay f32) -----
__global__ __launch_bounds__(640) void flowc2_kernel(
    const float* __restrict__ f, const float* __restrict__ wfT,
    const float* __restrict__ gfb, float* __restrict__ flows)
{
  __shared__ float tile[16*5*68];
  const int t = threadIdx.x;
  const int lb = xcd_swz(blockIdx.x);
  const int b = lb >> 6;
  const int y = lb & 63;
  const int o = t >> 6;
  const int pos = t & 63;

  float acc = gfb[o];

  #pragma unroll 1
  for (int ch = 0; ch < 2; ++ch) {
    const float* src = f + (b*32 + ch*16)*HH*WW;
    __syncthreads();
    for (int i = t; i < 16*5*68; i += 640) {
      int cin = i / 340, r2 = i % 340;
      int rr = r2 / 68, cc = r2 % 68;
      int gy = y + rr - 2, gx = cc - 2;
      tile[i] = (gy >= 0 && gy < HH && gx >= 0 && gx < WW)
                  ? src[cin*HH*WW + gy*WW + gx] : 0.f;
    }
    __syncthreads();
    const float* wbase = wfT + (ch*16*25)*10;
    #pragma unroll 1
    for (int ci = 0; ci < 16; ++ci) {
      #pragma unroll
      for (int kh = 0; kh < 5; ++kh) {
        #pragma unroll
        for (int kw = 0; kw < 5; ++kw) {
          float w = wbase[((ci*5 + kh)*5 + kw)*10 + o];
          acc = fmaf(w, tile[ci*340 + kh*68 + pos + kw], acc);
        }
      }
    }
  }
  flows[(b*10 + o)*HH*WW + y*WW + pos] = acc;
}

// ---- fuse7: 1024 thr, 16 waves; direct x-conv; coalesced hT gather ----
__global__ __launch_bounds__(1024, 8) void fuse7_kernel(
    const float* __restrict__ x, const float* __restrict__ hT,
    const float* __restrict__ flows,
    const unsigned short* __restrict__ erF, const unsigned short* __restrict__ ehF,
    const unsigned short* __restrict__ x2rF, const unsigned short* __restrict__ x2hF,
    const float* __restrict__ wxrb, const float* __restrict__ wxhb,
    const float* __restrict__ brs,  const float* __restrict__ bhs,
    float* __restrict__ out, int out_half)
{
  __shared__ __align__(16) char xtile[6*68*32];   // 13056 B
  __shared__ __align__(16) char warped[64*256];   // 16384 B
  __shared__ int   cidx[LNK*4*64];
  __shared__ float cwt[LNK*4*64];

  const int t = threadIdx.x;
  const int lb = xcd_swz(blockIdx.x);
  const int b = lb >> 6;
  const int y = lb & 63;
  const int lane = t & 63;
  const int w = t >> 6;            // 0..15
  const int wo = w & 7;            // o-stripe
  const int wp = w >> 3;           // pos half
  const int q = lane >> 4;
  const int s = q & 1;
  const int khq = q >> 1;

  if (t < 544) ((unsigned*)(xtile + 5*68*32))[t] = 0u;

  // stage x halo tile [6][68][16] bf16
  {
    const float* xp = x + b*CINX*HH*WW;
    for (int i = t; i < 5440; i += 1024) {
      int cin = i / 340, rc = i % 340;
      int r = rc / 68, c = rc % 68;
      int gy = y + r - 2, gx = c - 2;
      float v = (gy >= 0 && gy < HH && gx >= 0 && gx < WW)
                  ? xp[cin*4096 + gy*64 + gx] : 0.f;
      int byte = ((r*68 + c)*16 + cin)*2;
      *(unsigned short*)(xtile + SWZX(byte, c)) = f2b(v);
    }
  }

  // bilinear corners for 64 pos x 5 links
  if (t < 320) {
    int pos = t & 63; int l = t >> 6;
    float fx = flows[((b*2*LNK) + 2*l + 0)*HH*WW + y*WW + pos];
    float fy = flows[((b*2*LNK) + 2*l + 1)*HH*WW + y*WW + pos];
    float px = fx + (float)pos;
    float py = fy + (float)y;
    float x0f = floorf(px), y0f = floorf(py);
    float ax = px - x0f, ay = py - y0f;
    int ix0 = (int)x0f, iy0 = (int)y0f;
    #pragma unroll
    for (int k = 0; k < 4; ++k) {
      int dx = k & 1, dy = k >> 1;
      int ix = ix0 + dx, iy = iy0 + dy;
      float wgt = (dx ? ax : 1.f - ax) * (dy ? ay : 1.f - ay);
      bool inb = (ix >= 0 && ix < WW && iy >= 0 && iy < HH);
      int ixc = ix < 0 ? 0 : (ix > WW-1 ? WW-1 : ix);
      int iyc = iy < 0 ? 0 : (iy > HH-1 ? HH-1 : iy);
      cidx[(l*4 + k)*64 + pos] = iyc*WW + ixc;
      cwt [(l*4 + k)*64 + pos] = inb ? wgt : 0.f;
    }
  }
  __syncthreads();

  f32x4 accr[2], acch[2];
  #pragma unroll
  for (int f = 0; f < 2; ++f) {
    accr[f] = (f32x4){0.f,0.f,0.f,0.f};
    acch[f] = (f32x4){0.f,0.f,0.f,0.f};
  }

  // GEMM2: direct x-conv, 15 (kw,khp) steps x 2 col-frags x 2 gates
  #pragma unroll 1
  for (int kw = 0; kw < 5; ++kw) {
    #pragma unroll
    for (int khp = 0; khp < 3; ++khp) {
      bf16x8 ar = *(const bf16x8*)(x2rF + (((kw*3 + khp)*8 + wo)*512) + lane*8);
      bf16x8 ah = *(const bf16x8*)(x2hF + (((kw*3 + khp)*8 + wo)*512) + lane*8);
      int kh = khp*2 + khq;
      #pragma unroll
      for (int f = 0; f < 2; ++f) {
        int c = wp*32 + f*16 + (lane & 15) + kw;
        int byte = ((kh*68 + c)*16 + s*8)*2;
        bf16x8 bv = *(const bf16x8*)(xtile + SWZX(byte, c));
        accr[f] = MFMA(ar, bv, accr[f]);
        acch[f] = MFMA(ah, bv, acch[f]);
      }
    }
  }

  f32x4 tmph[2];
  tmph[0] = (f32x4){0.f,0.f,0.f,0.f};
  tmph[1] = (f32x4){0.f,0.f,0.f,0.f};

  // GEMM1: einsum, 5 chunks of K=128; coalesced gather from hT.
  const float* hTb = hT + (size_t)b*524288;
  const int gp  = t >> 4;
  const int sub = t & 15;
  #pragma unroll 1
  for (int l = 0; l < 5; ++l) {
    if (l) __syncthreads();
    float w0 = cwt[(l*4+0)*64 + gp], w1 = cwt[(l*4+1)*64 + gp];
    float w2 = cwt[(l*4+2)*64 + gp], w3 = cwt[(l*4+3)*64 + gp];
    int   i0 = cidx[(l*4+0)*64 + gp], i1 = cidx[(l*4+1)*64 + gp];
    int   i2 = cidx[(l*4+2)*64 + gp], i3 = cidx[(l*4+3)*64 + gp];
    const float* p0 = hTb + i0*128 + sub*8;
    const float* p1 = hTb + i1*128 + sub*8;
    const float* p2 = hTb + i2*128 + sub*8;
    const float* p3 = hTb + i3*128 + sub*8;
    unsigned pr[4];
    #pragma unroll
    for (int e4 = 0; e4 < 2; ++e4) {
      float4 c0 = *(const float4*)(p0 + e4*4);
      float4 c1 = *(const float4*)(p1 + e4*4);
      float4 c2 = *(const float4*)(p2 + e4*4);
      float4 c3 = *(const float4*)(p3 + e4*4);
      const float* c0p = (const float*)&c0;
      const float* c1p = (const float*)&c1;
      const float* c2p = (const float*)&c2;
      const float* c3p = (const float*)&c3;
      #pragma unroll
      for (int jp = 0; jp < 2; ++jp) {
        int e = jp << 1;
        float a0 = w0*c0p[e];   a0 = fmaf(w1, c1p[e], a0);
        a0 = fmaf(w2, c2p[e], a0); a0 = fmaf(w3, c3p[e], a0);
        float a1 = w0*c0p[e+1]; a1 = fmaf(w1, c1p[e+1], a1);
        a1 = fmaf(w2, c2p[e+1], a1); a1 = fmaf(w3, c3p[e+1], a1);
        pr[e4*2 + jp] = (unsigned)f2b(a0) | ((unsigned)f2b(a1) << 16);
      }
    }
    uint4 pv; pv.x = pr[0]; pv.y = pr[1]; pv.z = pr[2]; pv.w = pr[3];
    int cbyte = gp*256 + sub*16;
    *(uint4*)(warped + SWZ(cbyte, gp)) = pv;
    __syncthreads();
    #pragma unroll
    for (int ks = 0; ks < 4; ++ks) {
      bf16x8 ar = *(const bf16x8*)(erF + (((l << 2) + ks)*8 + wo)*512 + lane*8);
      bf16x8 ah = *(const bf16x8*)(ehF + (((l << 2) + ks)*8 + wo)*512 + lane*8);
      int k0 = (ks << 5) + (q << 3);
      #pragma unroll
      for (int f = 0; f < 2; ++f) {
        int col = wp*32 + (f << 4) + (lane & 15);
        bf16x8 bv = *(const bf16x8*)(warped + SWZ(col*256 + k0*2, col));
        accr[f] = MFMA(ar, bv, accr[f]);
        tmph[f] = MFMA(ah, bv, tmph[f]);
      }
    }
  }

  // epilogue: r=sigmoid(.), out = leaky(ch + r*th); z cancels.
  const int obase = (b*CHID)*HH*WW + y*WW;
  #pragma unroll
  for (int r = 0; r < 4; ++r) {
    int o = wo*16 + (q << 2) + r;
    float br_ = wxrb[o] + brs[o];
    float bh_ = wxhb[o];
    float bt_ = bhs[o];
    #pragma unroll
    for (int f = 0; f < 2; ++f) {
      int pos_ = wp*32 + (f << 4) + (lane & 15);
      float rg = 1.f / (1.f + expf(-(accr[f][r] + br_)));
      float hv = (acch[f][r] + bh_) + rg*(tmph[f][r] + bt_);
      hv = hv >= 0.f ? hv : 0.2f*hv;
      int idx = obase + o*HH*WW + pos_;
      out[idx] = hv;
      out[out_half + idx] = hv;
    }
  }
}

// ---------------- fuse3 (fallback when ws too small) -----------------------
__global__ __launch_bounds__(512, 4) void fuse3_kernel(
    const float* __restrict__ x, const float* __restrict__ h,
    const float* __restrict__ flows,
    const unsigned short* __restrict__ erF, const unsigned short* __restrict__ ehF,
    const unsigned short* __restrict__ xrF, const unsigned short* __restrict__ xhF,
    const float* __restrict__ wxrb, const float* __restrict__ wxhb,
    const float* __restrict__ brs,  const float* __restrict__ bhs,
    float* __restrict__ out, int out_half)
{
  __shared__ __align__(16) char smem[64*416*2];
  __shared__ int   cidx[LNK*4*64];
  __shared__ float cwt[LNK*4*64];

  const int t = threadIdx.x;
  const int lb = xcd_swz(blockIdx.x);
  const int b = lb >> 6;
  const int y = lb & 63;
  const int lane = t & 63;
  const int w = t >> 6;

  if (t < 320) {
    int pos = t & 63; int l = t >> 6;
    float fx = flows[((b*2*LNK) + 2*l + 0)*HH*WW + y*WW + pos];
    float fy = flows[((b*2*LNK) + 2*l + 1)*HH*WW + y*WW + pos];
    float px = fx + (float)pos;
    float py = fy + (float)y;
    float x0f = floorf(px), y0f = floorf(py);
    float ax = px - x0f, ay = py - y0f;
    int ix0 = (int)x0f, iy0 = (int)y0f;
    #pragma unroll
    for (int k = 0; k < 4; ++k) {
      int dx = k & 1, dy = k >> 1;
      int ix = ix0 + dx, iy = iy0 + dy;
      float wgt = (dx ? ax : 1.f - ax) * (dy ? ay : 1.f - ay);
      bool inb = (ix >= 0 && ix < WW && iy >= 0 && iy < HH);
      int ixc = ix < 0 ? 0 : (ix > WW-1 ? WW-1 : ix);
      int iyc = iy < 0 ? 0 : (iy > HH-1 ? HH-1 : iy);
      cidx[(l*4 + k)*64 + pos] = iyc*WW + ixc;
      cwt [(l*4 + k)*64 + pos] = inb ? wgt : 0.f;
    }
  }

  {
    const float* xp = x + b*CINX*HH*WW;
    for (int i = t; i < 64*416; i += 512) {
      int pos = i / 416; int k = i - pos*416;
      float val = 0.f;
      if (k < 400) {
        int cin = k / 25; int tap = k - cin*25;
        int kh = tap / 5; int kw = tap - kh*5;
        int gy = y + kh - 2, gxp = pos + kw - 2;
        if (gy >= 0 && gy < HH && gxp >= 0 && gxp < WW)
          val = xp[cin*4096 + gy*64 + gxp];
      }
      *(unsigned short*)(smem + SWZ(pos*832 + k*2, pos)) = f2b(val);
    }
  }
  __syncthreads();

  f32x4 accr[4], acch[4], tmph[4];
  #pragma unroll
  for (int f = 0; f < 4; ++f) {
    accr[f] = (f32x4){0.f,0.f,0.f,0.f};
    acch[f] = (f32x4){0.f,0.f,0.f,0.f};
    tmph[f] = (f32x4){0.f,0.f,0.f,0.f};
  }

  #pragma unroll 2
  for (int ks = 0; ks < 13; ++ks) {
    bf16x8 ar = *(const bf16x8*)(xrF + ((ks << 3) + w)*512 + lane*8);
    bf16x8 ah = *(const bf16x8*)(xhF + ((ks << 3) + w)*512 + lane*8);
    int k0 = (ks << 5) + ((lane >> 4) << 3);
    #pragma unroll
    for (int f = 0; f < 4; ++f) {
      int col = (f << 4) + (lane & 15);
      bf16x8 bv = *(const bf16x8*)(smem + SWZ(col*832 + k0*2, col));
      accr[f] = MFMA(ar, bv, accr[f]);
      acch[f] = MFMA(ah, bv, acch[f]);
    }
  }

  const float* hp = h + b*CHID*HH*WW;
  #pragma unroll 1
  for (int l = 0; l < 5; ++l) {
    __syncthreads();
    float w0 = cwt[(l*4+0)*64 + lane], w1 = cwt[(l*4+1)*64 + lane];
    float w2 = cwt[(l*4+2)*64 + lane], w3 = cwt[(l*4+3)*64 + lane];
    int   i0 = cidx[(l*4+0)*64 + lane], i1 = cidx[(l*4+1)*64 + lane];
    int   i2 = cidx[(l*4+2)*64 + lane], i3 = cidx[(l*4+3)*64 + lane];
    const float* hc = hp + (w << 4)*4096;
    #pragma unroll
    for (int jj = 0; jj < 8; ++jj) {
      const float* h0 = hc + (2*jj)*4096;
      const float* h1 = h0 + 4096;
      float a0 = w0*h0[i0]; a0 = fmaf(w1, h0[i1], a0);
      a0 = fmaf(w2, h0[i2], a0); a0 = fmaf(w3, h0[i3], a0);
      float a1 = w0*h1[i0]; a1 = fmaf(w1, h1[i1], a1);
      a1 = fmaf(w2, h1[i2], a1); a1 = fmaf(w3, h1[i3], a1);
      unsigned pr = (unsigned)f2b(a0) | ((unsigned)f2b(a1) << 16);
      int c0 = (w << 4) + 2*jj;
      *(unsigned*)(smem + SWZ(lane*256 + c0*2, lane)) = pr;
    }
    __syncthreads();
    #pragma unroll
    for (int ks = 0; ks < 4; ++ks) {
      bf16x8 ar = *(const bf16x8*)(erF + (((l << 2) + ks)*8 + w)*512 + lane*8);
      bf16x8 ah = *(const bf16x8*)(ehF + (((l << 2) + ks)*8 + w)*512 + lane*8);
      int k0 = (ks << 5) + ((lane >> 4) << 3);
      #pragma unroll
      for (int f = 0; f < 4; ++f) {
        int col = (f << 4) + (lane & 15);
        bf16x8 bv = *(const bf16x8*)(smem + SWZ(col*256 + k0*2, col));
        accr[f] = MFMA(ar, bv, accr[f]);
        tmph[f] = MFMA(ah, bv, tmph[f]);
      }
    }
  }

  const int obase = (b*CHID)*HH*WW + y*WW;
  #pragma unroll
  for (int r = 0; r < 4; ++r) {
    int o = (w << 4) + ((lane >> 4) << 2) + r;
    float br_ = wxrb[o] + brs[o];
    float bh_ = wxhb[o];
    float bt_ = bhs[o];
    #pragma unroll
    for (int f = 0; f < 4; ++f) {
      int pos_ = (f << 4) + (lane & 15);
      float rg = 1.f / (1.f + expf(-(accr[f][r] + br_)));
      float hv = (acch[f][r] + bh_) + rg*(tmph[f][r] + bt_);
      hv = hv >= 0.f ? hv : 0.2f*hv;
      int idx = obase + o*HH*WW + pos_;
      out[idx] = hv;
      out[out_half + idx] = hv;
    }
  }
}

extern "C" void kernel_launch(void* const* d_in, const int* in_sizes, int n_in,
                              void* d_out, int out_size, void* d_ws, size_t ws_size,
                              hipStream_t stream)
{
  const float* x     = (const float*)d_in[0];
  const float* h     = (const float*)d_in[1];
  const float* gx_w  = (const float*)d_in[2];
  const float* gx_b  = (const float*)d_in[3];
  const float* gh_w  = (const float*)d_in[4];
  const float* gh_b  = (const float*)d_in[5];
  const float* gf_w  = (const float*)d_in[6];
  const float* gf_b  = (const float*)d_in[7];
  const float* wxr_w = (const float*)d_in[10];
  const float* wxr_b = (const float*)d_in[11];
  const float* wxh_w = (const float*)d_in[12];
  const float* wxh_b = (const float*)d_in[13];
  const float* whr_w = (const float*)d_in[16];
  const float* whr_b = (const float*)d_in[17];
  const float* whh_w = (const float*)d_in[18];
  const float* whh_b = (const float*)d_in[19];
  float* out = (float*)d_out;
  float* wsf = (float*)d_ws;

  float* f_buf = wsf + OFF_F;
  float* flows = wsf + OFF_FLOWS;
  float* wfT   = wsf + OFF_WF;
  float* brs   = wsf + OFF_BRS;
  float* bhs   = wsf + OFF_BHS;
  unsigned short* erF  = (unsigned short*)(wsf + OFF_ERF);
  unsigned short* ehF  = (unsigned short*)(wsf + OFF_EHF);
  unsigned short* xrF  = (unsigned short*)(wsf + OFF_XRF);
  unsigned short* xhF  = (unsigned short*)(wsf + OFF_XHF);
  unsigned short* xgF  = (unsigned short*)(wsf + OFF_XGF);
  unsigned short* x2rF = (unsigned short*)(wsf + OFF_X2R);
  unsigned short* x2hF = (unsigned short*)(wsf + OFF_X2H);
  float* hT = wsf + OFF_HT;

  const bool big_ws = (ws_size >= NEED_WS_BYTES);

  prep_kernel<<<(P_X2 + 255)/256, 256, 0, stream>>>(
      wxr_w, wxh_w, whr_w, whh_w, whr_b, whh_b, gx_w, gh_w, gf_w,
      wfT, brs, bhs, erF, ehF, xrF, xhF, xgF, x2rF, x2hF);
  fgen4_kernel<<<BATCH*HH, 512, 0, stream>>>(x, h, xgF, gx_b, gh_b, f_buf,
                                             big_ws ? hT : nullptr);
  flowc2_kernel<<<BATCH*HH, 640, 0, stream>>>(f_buf, wfT, gf_b, flows);
  if (big_ws) {
    fuse7_kernel<<<BATCH*HH, 1024, 0, stream>>>(x, hT, flows, erF, ehF, x2rF, x2hF,
                                                wxr_b, wxh_b, brs, bhs, out, out_size/2);
  } else {
    fuse3_kernel<<<BATCH*HH, 512, 0, stream>>>(x, h, flows, erF, ehF, xrF, xhF,
                                               wxr_b, wxh_b, brs, bhs, out, out_size/2);
  }
}

// Round 19
// 236.893 us; speedup vs baseline: 1.1961x; 1.0349x over previous
//
#include <hip/hip_runtime.h>
#include <math.h>

#define HH 64
#define WW 64
#define BATCH 16
#define CINX 16
#define CHID 128
#define LNK 5

// ws layout (floats)
#define OFF_F      0
#define N_F        (BATCH*32*HH*WW)          // 2097152
#define OFF_FLOWS  (OFF_F + N_F)
#define N_FLOWS    (BATCH*2*LNK*HH*WW)       // 655360
#define OFF_WF     (OFF_FLOWS + N_FLOWS)     // 2752512
#define N_WF       (32*25*10)                // 8000
#define OFF_BRS    (OFF_WF + N_WF)
#define OFF_BHS    (OFF_BRS + 128)
#define OFF_ERF    (OFF_BHS + 128)           // einsum frags bf16 (81920 each gate)
#define OFF_EHF    (OFF_ERF + 40960)
#define OFF_XRF    (OFF_EHF + 40960)         // xconv im2col frags bf16 (fallback)
#define OFF_XHF    (OFF_XRF + 26624)
#define OFF_XGF    (OFF_XHF + 26624)         // fgen frags bf16 (138240)
#define OFF_X2R    (OFF_XGF + 69120)         // xconv direct frags bf16 (61440 each)
#define OFF_X2H    (OFF_X2R + 30720)
#define OFF_HT     (OFF_X2H + 30720)         // 3026496; hT f32 [b][y][x][c]
#define N_HT       (BATCH*HH*WW*CHID)        // 8388608 floats = 33.5 MB
#define NEED_WS_BYTES ((size_t)(OFF_HT + N_HT) * 4)   // ~45.7 MB

// prep region boundaries (element indices)
#define P_WF   8000
#define P_B    (P_WF + 128)                  // 8128
#define P_EF   (P_B + 81920)                 // 90048
#define P_XF   (P_EF + 53248)                // 143296
#define P_GF   (P_XF + 138240)               // 281536
#define P_X2   (P_GF + 61440)                // 342976

typedef short bf16x8 __attribute__((ext_vector_type(8)));
typedef float f32x4  __attribute__((ext_vector_type(4)));
#define MFMA(a,b,c) __builtin_amdgcn_mfma_f32_16x16x32_bf16((a),(b),(c),0,0,0)

__device__ __forceinline__ unsigned short f2b(float f) {
  unsigned u = __builtin_bit_cast(unsigned, f);
  u += 0x7fffu + ((u >> 16) & 1u);           // RNE
  return (unsigned short)(u >> 16);
}

#define SWZ(byte, row) ((byte) ^ (((row) & 7) << 4))
// tile swizzle: XOR byte bits 4,5 with c bits 0,2 (bijective; keeps 16B reads
// aligned). Measured r16: conflicts 12.65M -> 5.26M on fgen4 staging.
#define SWZX(byte, c) ((byte) ^ ((((c) & 1) << 4) ^ ((((c) >> 2) & 1) << 5)))

// XCD-aware bijective swizzle: grid = 1024 = 8 XCDs x 128.
__device__ __forceinline__ int xcd_swz(int p) {
  return (p & 7) * 128 + (p >> 3);
}

// ---------------- prep: fragment weights, pre-sum biases --------
__global__ __launch_bounds__(256) void prep_kernel(
    const float* __restrict__ wxr_w, const float* __restrict__ wxh_w,
    const float* __restrict__ whr_w, const float* __restrict__ whh_w,
    const float* __restrict__ whr_b, const float* __restrict__ whh_b,
    const float* __restrict__ gx_w,  const float* __restrict__ gh_w,
    const float* __restrict__ gf_w,
    float* __restrict__ wfT,
    float* __restrict__ brs,  float* __restrict__ bhs,
    unsigned short* __restrict__ erF, unsigned short* __restrict__ ehF,
    unsigned short* __restrict__ xrF, unsigned short* __restrict__ xhF,
    unsigned short* __restrict__ xgF,
    unsigned short* __restrict__ x2rF, unsigned short* __restrict__ x2hF)
{
  int i = blockIdx.x * 256 + threadIdx.x;
  if (i < P_WF) {
    int k = i / 10, o = i % 10;              // wfT[k][o], k = cin*25+tap
    int cin = k / 25, tap = k % 25;
    wfT[i] = gf_w[(o*32 + cin)*25 + tap];
  } else if (i < P_B) {
    int o = i - P_WF;
    float sr = 0.f, sh = 0.f;
    for (int l = 0; l < LNK; ++l) { sr += whr_b[l*128 + o]; sh += whh_b[l*128 + o]; }
    brs[o] = sr; bhs[o] = sh;
  } else if (i < P_EF) {
    // einsum A-frags: j = (((l*4+ks)*8+m)*64 + lane)*8 + jj
    int j = i - P_B;
    int jj = j & 7, lane = (j >> 3) & 63, m = (j >> 9) & 7, ks = (j >> 12) & 3, l = j >> 14;
    int o = m*16 + (lane & 15);
    int c = ks*32 + ((lane >> 4) << 3) + jj;
    erF[j] = f2b(whr_w[(l*128 + o)*128 + c]);
    ehF[j] = f2b(whh_w[(l*128 + o)*128 + c]);
  } else if (i < P_XF) {
    // xconv im2col A-frags (fuse3 fallback): k padded 400->416
    int j = i - P_EF;
    int jj = j & 7, lane = (j >> 3) & 63, m = (j >> 9) & 7, ks = j >> 12;
    int o = m*16 + (lane & 15);
    int k = ks*32 + ((lane >> 4) << 3) + jj;
    xrF[j] = (k < 400) ? f2b(wxr_w[o*400 + k]) : (unsigned short)0;
    xhF[j] = (k < 400) ? f2b(wxh_w[o*400 + k]) : (unsigned short)0;
  } else if (i < P_GF) {
    // fgen A-frags: j = ((((ch*15 + kw*3 + khp)*2 + mo)*64 + lane)*8 + jj
    int j = i - P_XF;
    int jj = j & 7, lane = (j >> 3) & 63;
    int r2 = j >> 9;
    int mo = r2 & 1;
    int r3 = r2 >> 1;
    int khp = r3 % 3, kw = (r3 / 3) % 5, ch = r3 / 15;
    int q = lane >> 4;
    int k = q*8 + jj;
    int kh = khp*2 + (k >> 4);
    int cin_l = k & 15;
    int o = mo*16 + (lane & 15);
    float val = 0.f;
    if (kh < 5) {
      int tap = kh*5 + kw;
      val = (ch == 0) ? gx_w[(o*CINX + cin_l)*25 + tap]
                      : gh_w[(o*CHID + (ch-1)*16 + cin_l)*25 + tap];
    }
    xgF[j] = f2b(val);
  } else if (i < P_X2) {
    // xconv direct-conv A-frags: j = ((((kw*3+khp)*8 + wv)*64 + lane)*8 + jj
    int j = i - P_GF;
    int jj = j & 7, lane = (j >> 3) & 63;
    int wv = (j >> 9) & 7;
    int r3 = j >> 12;                        // 0..14
    int khp = r3 % 3, kw = r3 / 3;
    int o = wv*16 + (lane & 15);
    int k = ((lane >> 4) << 3) + jj;
    int kh = khp*2 + (k >> 4);
    int cin = k & 15;
    float vr = 0.f, vh = 0.f;
    if (kh < 5) {
      int off = o*400 + cin*25 + kh*5 + kw;
      vr = wxr_w[off]; vh = wxh_w[off];
    }
    x2rF[j] = f2b(vr); x2hF[j] = f2b(vh);
  }
}

// ------- fgen4: dbuf MFMA conv + fused hT emission; quad-vector staging ----
// Halo columns (c<2 or c>=66) are identically zero -> zero whole tile once,
// stage only the 64 valid columns as 16B-aligned float4 quads.
__global__ __launch_bounds__(512, 4) void fgen4_kernel(
    const float* __restrict__ x, const float* __restrict__ h,
    const unsigned short* __restrict__ xgF,
    const float* __restrict__ gxb, const float* __restrict__ ghb,
    float* __restrict__ f, float* __restrict__ hTout)
{
  __shared__ __align__(16) char tile[2][6*68*32];   // 26112 B
  __shared__ __align__(16) float crow[2][16][68];   // 8704 B (16B-aligned rows)
  const int t = threadIdx.x;
  const int lb = xcd_swz(blockIdx.x);
  const int b = lb >> 6;
  const int y = lb & 63;
  const int lane = t & 63;
  const int w = t >> 6;
  const int mo = w >> 2, nf = w & 3;
  const int q = lane >> 4;
  const int s = q & 1;
  const int khq = q >> 1;
  const int cbase = nf*16 + (lane & 15);

  // zero BOTH tile buffers fully (halo cols + invalid rows stay 0 forever)
  {
    uint4 z = (uint4){0u,0u,0u,0u};
    uint4* tp = (uint4*)&tile[0][0];
    for (int i = t; i < 1632; i += 512) tp[i] = z;
  }
  __syncthreads();

  const float* xp = x + b*CINX*HH*WW;
  const float* hp = h + b*CHID*HH*WW;
  float* hTrow = hTout ? hTout + (size_t)lb*8192 : nullptr;

  // quad staging: i -> (cin, r, g0); 1280 quads; only valid rows written.
  auto stage = [&](int ch, char* buf, float* crowp) {
    const float* src = (ch == 0) ? xp : hp + (ch - 1)*16*4096;
    for (int i = t; i < 1280; i += 512) {
      int cin = i / 80, rem = i % 80;
      int r = rem >> 4;
      int g0 = (rem & 15) << 2;
      int gy = y + r - 2;
      if (gy < 0 || gy >= HH) continue;
      float4 v = *(const float4*)(src + cin*4096 + gy*64 + g0);
      const float* vp = (const float*)&v;
      if (crowp && r == 2)
        *(float4*)(crowp + cin*68 + g0) = v;
      #pragma unroll
      for (int j = 0; j < 4; ++j) {
        int c = g0 + 2 + j;
        int byte = ((r*68 + c)*16 + cin)*2;
        *(unsigned short*)(buf + SWZX(byte, c)) = f2b(vp[j]);
      }
    }
  };

  f32x4 acc = (f32x4){0.f, 0.f, 0.f, 0.f};

  stage(0, tile[0], nullptr);
  __syncthreads();

  #pragma unroll 1
  for (int ch = 0; ch < 9; ++ch) {
    // flush chunk ch's center row (filled during stage(ch), synced) before
    // stage(ch+1) runs; stage(ch+1) writes crow[(ch+1)&1] != crow[ch&1].
    if (hTrow && ch > 0) {
      int xx = t >> 3, c2 = (t & 7) << 1;
      float* dst = hTrow + xx*128 + (ch-1)*16 + c2;
      dst[0] = crow[ch & 1][c2][xx];
      dst[1] = crow[ch & 1][c2+1][xx];
    }
    if (ch < 8) stage(ch + 1, tile[(ch + 1) & 1],
                      (hTrow) ? &crow[(ch + 1) & 1][0][0] : nullptr);
    const char* tb = tile[ch & 1];
    #pragma unroll
    for (int kw = 0; kw < 5; ++kw) {
      #pragma unroll
      for (int khp = 0; khp < 3; ++khp) {
        bf16x8 av = *(const bf16x8*)(xgF + (((ch*15 + kw*3 + khp)*2 + mo)*512) + lane*8);
        int c = cbase + kw;
        int kh = khp*2 + khq;
        int byte = ((kh*68 + c)*16 + s*8)*2;
        bf16x8 bv = *(const bf16x8*)(tb + SWZX(byte, c));
        acc = MFMA(av, bv, acc);
      }
    }
    __syncthreads();
  }

  #pragma unroll
  for (int r = 0; r < 4; ++r) {
    int o = mo*16 + q*4 + r;
    int pos = nf*16 + (lane & 15);
    float a = acc[r] + gxb[o] + ghb[o];
    f[(b*32 + o)*HH*WW + y*WW + pos] = a >= 0.f ? a : 0.2f*a;
  }
}

// ------- flowc2: flows = conv(f, gf), scalar f32 (flows MUST stay f32) -----
__global__ __launch_bounds__(640) void flowc2_kernel(
    const float* __restrict__ f, const float* __restrict__ wfT,
    const float* __restrict__ gfb, float* __restrict__ flows)
{
  __shared__ float tile[16*5*68];
  const int t = threadIdx.x;
  const int lb = xcd_swz(blockIdx.x);
  const int b = lb >> 6;
  const int y = lb & 63;
  const int o = t >> 6;
  const int pos = t & 63;

  float acc = gfb[o];

  #pragma unroll 1
  for (int ch = 0; ch < 2; ++ch) {
    const float* src = f + (b*32 + ch*16)*HH*WW;
    __syncthreads();
    for (int i = t; i < 16*5*68; i += 640) {
      int cin = i / 340, r2 = i % 340;
      int rr = r2 / 68, cc = r2 % 68;
      int gy = y + rr - 2, gx = cc - 2;
      tile[i] = (gy >= 0 && gy < HH && gx >= 0 && gx < WW)
                  ? src[cin*HH*WW + gy*WW + gx] : 0.f;
    }
    __syncthreads();
    const float* wbase = wfT + (ch*16*25)*10;
    #pragma unroll 1
    for (int ci = 0; ci < 16; ++ci) {
      #pragma unroll
      for (int kh = 0; kh < 5; ++kh) {
        #pragma unroll
        for (int kw = 0; kw < 5; ++kw) {
          float w = wbase[((ci*5 + kh)*5 + kw)*10 + o];
          acc = fmaf(w, tile[ci*340 + kh*68 + pos + kw], acc);
        }
      }
    }
  }
  flows[(b*10 + o)*HH*WW + y*WW + pos] = acc;
}

// ---- fuse7: 1024 thr, 16 waves; direct x-conv; coalesced hT gather ----
__global__ __launch_bounds__(1024, 8) void fuse7_kernel(
    const float* __restrict__ x, const float* __restrict__ hT,
    const float* __restrict__ flows,
    const unsigned short* __restrict__ erF, const unsigned short* __restrict__ ehF,
    const unsigned short* __restrict__ x2rF, const unsigned short* __restrict__ x2hF,
    const float* __restrict__ wxrb, const float* __restrict__ wxhb,
    const float* __restrict__ brs,  const float* __restrict__ bhs,
    float* __restrict__ out, int out_half)
{
  __shared__ __align__(16) char xtile[6*68*32];   // 13056 B
  __shared__ __align__(16) char warped[64*256];   // 16384 B
  __shared__ int   cidx[LNK*4*64];
  __shared__ float cwt[LNK*4*64];

  const int t = threadIdx.x;
  const int lb = xcd_swz(blockIdx.x);
  const int b = lb >> 6;
  const int y = lb & 63;
  const int lane = t & 63;
  const int w = t >> 6;            // 0..15
  const int wo = w & 7;            // o-stripe
  const int wp = w >> 3;           // pos half
  const int q = lane >> 4;
  const int s = q & 1;
  const int khq = q >> 1;

  // zero full xtile once (halo cols + invalid rows stay 0)
  if (t < 816) ((uint4*)xtile)[t] = (uint4){0u,0u,0u,0u};

  // bilinear corners for 64 pos x 5 links (disjoint from xtile)
  if (t < 320) {
    int pos = t & 63; int l = t >> 6;
    float fx = flows[((b*2*LNK) + 2*l + 0)*HH*WW + y*WW + pos];
    float fy = flows[((b*2*LNK) + 2*l + 1)*HH*WW + y*WW + pos];
    float px = fx + (float)pos;
    float py = fy + (float)y;
    float x0f = floorf(px), y0f = floorf(py);
    float ax = px - x0f, ay = py - y0f;
    int ix0 = (int)x0f, iy0 = (int)y0f;
    #pragma unroll
    for (int k = 0; k < 4; ++k) {
      int dx = k & 1, dy = k >> 1;
      int ix = ix0 + dx, iy = iy0 + dy;
      float wgt = (dx ? ax : 1.f - ax) * (dy ? ay : 1.f - ay);
      bool inb = (ix >= 0 && ix < WW && iy >= 0 && iy < HH);
      int ixc = ix < 0 ? 0 : (ix > WW-1 ? WW-1 : ix);
      int iyc = iy < 0 ? 0 : (iy > HH-1 ? HH-1 : iy);
      cidx[(l*4 + k)*64 + pos] = iyc*WW + ixc;
      cwt [(l*4 + k)*64 + pos] = inb ? wgt : 0.f;
    }
  }
  __syncthreads();   // xtile zero done

  // stage x halo tile: quad-vector path (valid rows/cols only)
  {
    const float* xp = x + b*CINX*HH*WW;
    for (int i = t; i < 1280; i += 1024) {
      int cin = i / 80, rem = i % 80;
      int r = rem >> 4;
      int g0 = (rem & 15) << 2;
      int gy = y + r - 2;
      if (gy < 0 || gy >= HH) continue;
      float4 v = *(const float4*)(xp + cin*4096 + gy*64 + g0);
      const float* vp = (const float*)&v;
      #pragma unroll
      for (int j = 0; j < 4; ++j) {
        int c = g0 + 2 + j;
        int byte = ((r*68 + c)*16 + cin)*2;
        *(unsigned short*)(xtile + SWZX(byte, c)) = f2b(vp[j]);
      }
    }
  }
  __syncthreads();   // xtile + corners ready

  f32x4 accr[2], acch[2];
  #pragma unroll
  for (int f = 0; f < 2; ++f) {
    accr[f] = (f32x4){0.f,0.f,0.f,0.f};
    acch[f] = (f32x4){0.f,0.f,0.f,0.f};
  }

  // GEMM2: direct x-conv, 15 (kw,khp) steps x 2 col-frags x 2 gates
  #pragma unroll 1
  for (int kw = 0; kw < 5; ++kw) {
    #pragma unroll
    for (int khp = 0; khp < 3; ++khp) {
      bf16x8 ar = *(const bf16x8*)(x2rF + (((kw*3 + khp)*8 + wo)*512) + lane*8);
      bf16x8 ah = *(const bf16x8*)(x2hF + (((kw*3 + khp)*8 + wo)*512) + lane*8);
      int kh = khp*2 + khq;
      #pragma unroll
      for (int f = 0; f < 2; ++f) {
        int c = wp*32 + f*16 + (lane & 15) + kw;
        int byte = ((kh*68 + c)*16 + s*8)*2;
        bf16x8 bv = *(const bf16x8*)(xtile + SWZX(byte, c));
        accr[f] = MFMA(ar, bv, accr[f]);
        acch[f] = MFMA(ah, bv, acch[f]);
      }
    }
  }

  f32x4 tmph[2];
  tmph[0] = (f32x4){0.f,0.f,0.f,0.f};
  tmph[1] = (f32x4){0.f,0.f,0.f,0.f};

  // GEMM1: einsum, 5 chunks of K=128; coalesced gather from hT.
  const float* hTb = hT + (size_t)b*524288;
  const int gp  = t >> 4;
  const int sub = t & 15;
  #pragma unroll 1
  for (int l = 0; l < 5; ++l) {
    if (l) __syncthreads();
    float w0 = cwt[(l*4+0)*64 + gp], w1 = cwt[(l*4+1)*64 + gp];
    float w2 = cwt[(l*4+2)*64 + gp], w3 = cwt[(l*4+3)*64 + gp];
    int   i0 = cidx[(l*4+0)*64 + gp], i1 = cidx[(l*4+1)*64 + gp];
    int   i2 = cidx[(l*4+2)*64 + gp], i3 = cidx[(l*4+3)*64 + gp];
    const float* p0 = hTb + i0*128 + sub*8;
    const float* p1 = hTb + i1*128 + sub*8;
    const float* p2 = hTb + i2*128 + sub*8;
    const float* p3 = hTb + i3*128 + sub*8;
    unsigned pr[4];
    #pragma unroll
    for (int e4 = 0; e4 < 2; ++e4) {
      float4 c0 = *(const float4*)(p0 + e4*4);
      float4 c1 = *(const float4*)(p1 + e4*4);
      float4 c2 = *(const float4*)(p2 + e4*4);
      float4 c3 = *(const float4*)(p3 + e4*4);
      const float* c0p = (const float*)&c0;
      const float* c1p = (const float*)&c1;
      const float* c2p = (const float*)&c2;
      const float* c3p = (const float*)&c3;
      #pragma unroll
      for (int jp = 0; jp < 2; ++jp) {
        int e = jp << 1;
        float a0 = w0*c0p[e];   a0 = fmaf(w1, c1p[e], a0);
        a0 = fmaf(w2, c2p[e], a0); a0 = fmaf(w3, c3p[e], a0);
        float a1 = w0*c0p[e+1]; a1 = fmaf(w1, c1p[e+1], a1);
        a1 = fmaf(w2, c2p[e+1], a1); a1 = fmaf(w3, c3p[e+1], a1);
        pr[e4*2 + jp] = (unsigned)f2b(a0) | ((unsigned)f2b(a1) << 16);
      }
    }
    uint4 pv; pv.x = pr[0]; pv.y = pr[1]; pv.z = pr[2]; pv.w = pr[3];
    int cbyte = gp*256 + sub*16;
    *(uint4*)(warped + SWZ(cbyte, gp)) = pv;
    __syncthreads();
    #pragma unroll
    for (int ks = 0; ks < 4; ++ks) {
      bf16x8 ar = *(const bf16x8*)(erF + (((l << 2) + ks)*8 + wo)*512 + lane*8);
      bf16x8 ah = *(const bf16x8*)(ehF + (((l << 2) + ks)*8 + wo)*512 + lane*8);
      int k0 = (ks << 5) + (q << 3);
      #pragma unroll
      for (int f = 0; f < 2; ++f) {
        int col = wp*32 + (f << 4) + (lane & 15);
        bf16x8 bv = *(const bf16x8*)(warped + SWZ(col*256 + k0*2, col));
        accr[f] = MFMA(ar, bv, accr[f]);
        tmph[f] = MFMA(ah, bv, tmph[f]);
      }
    }
  }

  // epilogue: r=sigmoid(.), out = leaky(ch + r*th); z cancels.
  const int obase = (b*CHID)*HH*WW + y*WW;
  #pragma unroll
  for (int r = 0; r < 4; ++r) {
    int o = wo*16 + (q << 2) + r;
    float br_ = wxrb[o] + brs[o];
    float bh_ = wxhb[o];
    float bt_ = bhs[o];
    #pragma unroll
    for (int f = 0; f < 2; ++f) {
      int pos_ = wp*32 + (f << 4) + (lane & 15);
      float rg = 1.f / (1.f + expf(-(accr[f][r] + br_)));
      float hv = (acch[f][r] + bh_) + rg*(tmph[f][r] + bt_);
      hv = hv >= 0.f ? hv : 0.2f*hv;
      int idx = obase + o*HH*WW + pos_;
      out[idx] = hv;
      out[out_half + idx] = hv;
    }
  }
}

// ---------------- fuse3 (fallback when ws too small) -----------------------
__global__ __launch_bounds__(512, 4) void fuse3_kernel(
    const float* __restrict__ x, const float* __restrict__ h,
    const float* __restrict__ flows,
    const unsigned short* __restrict__ erF, const unsigned short* __restrict__ ehF,
    const unsigned short* __restrict__ xrF, const unsigned short* __restrict__ xhF,
    const float* __restrict__ wxrb, const float* __restrict__ wxhb,
    const float* __restrict__ brs,  const float* __restrict__ bhs,
    float* __restrict__ out, int out_half)
{
  __shared__ __align__(16) char smem[64*416*2];
  __shared__ int   cidx[LNK*4*64];
  __shared__ float cwt[LNK*4*64];

  const int t = threadIdx.x;
  const int lb = xcd_swz(blockIdx.x);
  const int b = lb >> 6;
  const int y = lb & 63;
  const int lane = t & 63;
  const int w = t >> 6;

  if (t < 320) {
    int pos = t & 63; int l = t >> 6;
    float fx = flows[((b*2*LNK) + 2*l + 0)*HH*WW + y*WW + pos];
    float fy = flows[((b*2*LNK) + 2*l + 1)*HH*WW + y*WW + pos];
    float px = fx + (float)pos;
    float py = fy + (float)y;
    float x0f = floorf(px), y0f = floorf(py);
    float ax = px - x0f, ay = py - y0f;
    int ix0 = (int)x0f, iy0 = (int)y0f;
    #pragma unroll
    for (int k = 0; k < 4; ++k) {
      int dx = k & 1, dy = k >> 1;
      int ix = ix0 + dx, iy = iy0 + dy;
      float wgt = (dx ? ax : 1.f - ax) * (dy ? ay : 1.f - ay);
      bool inb = (ix >= 0 && ix < WW && iy >= 0 && iy < HH);
      int ixc = ix < 0 ? 0 : (ix > WW-1 ? WW-1 : ix);
      int iyc = iy < 0 ? 0 : (iy > HH-1 ? HH-1 : iy);
      cidx[(l*4 + k)*64 + pos] = iyc*WW + ixc;
      cwt [(l*4 + k)*64 + pos] = inb ? wgt : 0.f;
    }
  }

  {
    const float* xp = x + b*CINX*HH*WW;
    for (int i = t; i < 64*416; i += 512) {
      int pos = i / 416; int k = i - pos*416;
      float val = 0.f;
      if (k < 400) {
        int cin = k / 25; int tap = k - cin*25;
        int kh = tap / 5; int kw = tap - kh*5;
        int gy = y + kh - 2, gxp = pos + kw - 2;
        if (gy >= 0 && gy < HH && gxp >= 0 && gxp < WW)
          val = xp[cin*4096 + gy*64 + gxp];
      }
      *(unsigned short*)(smem + SWZ(pos*832 + k*2, pos)) = f2b(val);
    }
  }
  __syncthreads();

  f32x4 accr[4], acch[4], tmph[4];
  #pragma unroll
  for (int f = 0; f < 4; ++f) {
    accr[f] = (f32x4){0.f,0.f,0.f,0.f};
    acch[f] = (f32x4){0.f,0.f,0.f,0.f};
    tmph[f] = (f32x4){0.f,0.f,0.f,0.f};
  }

  #pragma unroll 2
  for (int ks = 0; ks < 13; ++ks) {
    bf16x8 ar = *(const bf16x8*)(xrF + ((ks << 3) + w)*512 + lane*8);
    bf16x8 ah = *(const bf16x8*)(xhF + ((ks << 3) + w)*512 + lane*8);
    int k0 = (ks << 5) + ((lane >> 4) << 3);
    #pragma unroll
    for (int f = 0; f < 4; ++f) {
      int col = (f << 4) + (lane & 15);
      bf16x8 bv = *(const bf16x8*)(smem + SWZ(col*832 + k0*2, col));
      accr[f] = MFMA(ar, bv, accr[f]);
      acch[f] = MFMA(ah, bv, acch[f]);
    }
  }

  const float* hp = h + b*CHID*HH*WW;
  #pragma unroll 1
  for (int l = 0; l < 5; ++l) {
    __syncthreads();
    float w0 = cwt[(l*4+0)*64 + lane], w1 = cwt[(l*4+1)*64 + lane];
    float w2 = cwt[(l*4+2)*64 + lane], w3 = cwt[(l*4+3)*64 + lane];
    int   i0 = cidx[(l*4+0)*64 + lane], i1 = cidx[(l*4+1)*64 + lane];
    int   i2 = cidx[(l*4+2)*64 + lane], i3 = cidx[(l*4+3)*64 + lane];
    const float* hc = hp + (w << 4)*4096;
    #pragma unroll
    for (int jj = 0; jj < 8; ++jj) {
      const float* h0 = hc + (2*jj)*4096;
      const float* h1 = h0 + 4096;
      float a0 = w0*h0[i0]; a0 = fmaf(w1, h0[i1], a0);
      a0 = fmaf(w2, h0[i2], a0); a0 = fmaf(w3, h0[i3], a0);
      float a1 = w0*h1[i0]; a1 = fmaf(w1, h1[i1], a1);
      a1 = fmaf(w2, h1[i2], a1); a1 = fmaf(w3, h1[i3], a1);
      unsigned pr = (unsigned)f2b(a0) | ((unsigned)f2b(a1) << 16);
      int c0 = (w << 4) + 2*jj;
      *(unsigned*)(smem + SWZ(lane*256 + c0*2, lane)) = pr;
    }
    __syncthreads();
    #pragma unroll
    for (int ks = 0; ks < 4; ++ks) {
      bf16x8 ar = *(const bf16x8*)(erF + (((l << 2) + ks)*8 + w)*512 + lane*8);
      bf16x8 ah = *(const bf16x8*)(ehF + (((l << 2) + ks)*8 + w)*512 + lane*8);
      int k0 = (ks << 5) + ((lane >> 4) << 3);
      #pragma unroll
      for (int f = 0; f < 4; ++f) {
        int col = (f << 4) + (lane & 15);
        bf16x8 bv = *(const bf16x8*)(smem + SWZ(col*256 + k0*2, col));
        accr[f] = MFMA(ar, bv, accr[f]);
        tmph[f] = MFMA(ah, bv, tmph[f]);
      }
    }
  }

  const int obase = (b*CHID)*HH*WW + y*WW;
  #pragma unroll
  for (int r = 0; r < 4; ++r) {
    int o = (w << 4) + ((lane >> 4) << 2) + r;
    float br_ = wxrb[o] + brs[o];
    float bh_ = wxhb[o];
    float bt_ = bhs[o];
    #pragma unroll
    for (int f = 0; f < 4; ++f) {
      int pos_ = (f << 4) + (lane & 15);
      float rg = 1.f / (1.f + expf(-(accr[f][r] + br_)));
      float hv = (acch[f][r] + bh_) + rg*(tmph[f][r] + bt_);
      hv = hv >= 0.f ? hv : 0.2f*hv;
      int idx = obase + o*HH*WW + pos_;
      out[idx] = hv;
      out[out_half + idx] = hv;
    }
  }
}

extern "C" void kernel_launch(void* const* d_in, const int* in_sizes, int n_in,
                              void* d_out, int out_size, void* d_ws, size_t ws_size,
                              hipStream_t stream)
{
  const float* x     = (const float*)d_in[0];
  const float* h     = (const float*)d_in[1];
  const float* gx_w  = (const float*)d_in[2];
  const float* gx_b  = (const float*)d_in[3];
  const float* gh_w  = (const float*)d_in[4];
  const float* gh_b  = (const float*)d_in[5];
  const float* gf_w  = (const float*)d_in[6];
  const float* gf_b  = (const float*)d_in[7];
  const float* wxr_w = (const float*)d_in[10];
  const float* wxr_b = (const float*)d_in[11];
  const float* wxh_w = (const float*)d_in[12];
  const float* wxh_b = (const float*)d_in[13];
  const float* whr_w = (const float*)d_in[16];
  const float* whr_b = (const float*)d_in[17];
  const float* whh_w = (const float*)d_in[18];
  const float* whh_b = (const float*)d_in[19];
  float* out = (float*)d_out;
  float* wsf = (float*)d_ws;

  float* f_buf = wsf + OFF_F;
  float* flows = wsf + OFF_FLOWS;
  float* wfT   = wsf + OFF_WF;
  float* brs   = wsf + OFF_BRS;
  float* bhs   = wsf + OFF_BHS;
  unsigned short* erF  = (unsigned short*)(wsf + OFF_ERF);
  unsigned short* ehF  = (unsigned short*)(wsf + OFF_EHF);
  unsigned short* xrF  = (unsigned short*)(wsf + OFF_XRF);
  unsigned short* xhF  = (unsigned short*)(wsf + OFF_XHF);
  unsigned short* xgF  = (unsigned short*)(wsf + OFF_XGF);
  unsigned short* x2rF = (unsigned short*)(wsf + OFF_X2R);
  unsigned short* x2hF = (unsigned short*)(wsf + OFF_X2H);
  float* hT = wsf + OFF_HT;

  const bool big_ws = (ws_size >= NEED_WS_BYTES);

  prep_kernel<<<(P_X2 + 255)/256, 256, 0, stream>>>(
      wxr_w, wxh_w, whr_w, whh_w, whr_b, whh_b, gx_w, gh_w, gf_w,
      wfT, brs, bhs, erF, ehF, xrF, xhF, xgF, x2rF, x2hF);
  fgen4_kernel<<<BATCH*HH, 512, 0, stream>>>(x, h, xgF, gx_b, gh_b, f_buf,
                                             big_ws ? hT : nullptr);
  flowc2_kernel<<<BATCH*HH, 640, 0, stream>>>(f_buf, wfT, gf_b, flows);
  if (big_ws) {
    fuse7_kernel<<<BATCH*HH, 1024, 0, stream>>>(x, hT, flows, erF, ehF, x2rF, x2hF,
                                                wxr_b, wxh_b, brs, bhs, out, out_size/2);
  } else {
    fuse3_kernel<<<BATCH*HH, 512, 0, stream>>>(x, h, flows, erF, ehF, xrF, xhF,
                                               wxr_b, wxh_b, brs, bhs, out, out_size/2);
  }
}